// Round 1
// baseline (775.981 us; speedup 1.0000x reference)
//
#include <hip/hip_runtime.h>
#include <hip/hip_bf16.h>

typedef __attribute__((ext_vector_type(8))) short short8;
typedef __attribute__((ext_vector_type(4))) float floatx4;
typedef unsigned short u16;
typedef unsigned int u32;

#define TM 128         // edges per block
#define D 128          // IN == OUT == 128
#define LDSX 136       // padded bf16 row stride (elements) for x/w tiles
#define LDSG 132       // padded f32 row stride (elements) for g tile

static __device__ __forceinline__ u16 f2bf(float f) {
  union { float f; u32 u; } v; v.f = f;
  u32 r = v.u + 0x7fffu + ((v.u >> 16) & 1u);   // RNE round to bf16
  return (u16)(r >> 16);
}

// ---------------- prep: zero S, build W1^T in bf16 ----------------
__global__ void prep_kernel(const float* __restrict__ W1, u16* __restrict__ W1T,
                            float* __restrict__ S, int nS)
{
  int t = blockIdx.x * blockDim.x + threadIdx.x;
  if (t < D * D) {
    int k = t >> 7;          // W1 row (input dim)
    int n = t & (D - 1);     // W1 col (output dim)
    W1T[n * D + k] = f2bf(W1[t]);
  }
  if (t < nS) S[t] = 0.f;
}

// ---------------- main: g = relu(x@W1+b1), segment-sum into S ----------------
__global__ __launch_bounds__(256, 2)
void fused_mlp_segsum(const float* __restrict__ x1,
                      const int* __restrict__ slices,
                      const u16* __restrict__ W1T,
                      const float* __restrict__ b1,
                      float* __restrict__ S,
                      int E, int B)
{
  __shared__ __align__(16) char smem[2 * TM * LDSX * 2];  // 69632 B, reused
  __shared__ float partial[4 * D];
  u16* xt = (u16*)smem;                 // [TM][LDSX] bf16 bits
  u16* wt = (u16*)smem + TM * LDSX;     // [D][LDSX]  bf16 bits (W1^T: [n][k])
  float* g = (float*)smem;              // [TM][LDSG] f32 (reuse after MFMA)

  const int tid = threadIdx.x;
  const int r0 = blockIdx.x * TM;

  // stage W1^T (bf16 [n][k] row-major, from ws) into padded LDS
  #pragma unroll
  for (int i = 0; i < 8; ++i) {
    int f = tid + i * 256;              // 0..2047 chunks of 8 u16
    int n = f >> 4;
    int c = (f & 15) * 8;
    uint4 w = *(const uint4*)(W1T + n * D + c);
    *(uint4*)(wt + n * LDSX + c) = w;
  }
  // stage x rows [r0, r0+TM) as bf16 (zero-pad past E)
  #pragma unroll
  for (int i = 0; i < 16; ++i) {
    int f = tid + i * 256;              // 0..4095 chunks of 4 f32
    int r = f >> 5;
    int c = (f & 31) * 4;
    int row = r0 + r;
    float4 v;
    if (row < E) v = *(const float4*)(x1 + (size_t)row * D + c);
    else         v = make_float4(0.f, 0.f, 0.f, 0.f);
    uint2 pk;
    pk.x = (u32)f2bf(v.x) | ((u32)f2bf(v.y) << 16);
    pk.y = (u32)f2bf(v.z) | ((u32)f2bf(v.w) << 16);
    *(uint2*)(xt + r * LDSX + c) = pk;
  }
  __syncthreads();

  const int wave = tid >> 6;
  const int lane = tid & 63;
  const int quad = lane >> 4;
  const int l16  = lane & 15;

  floatx4 acc[2][8];
  #pragma unroll
  for (int a = 0; a < 2; ++a)
    #pragma unroll
    for (int b = 0; b < 8; ++b)
      acc[a][b] = (floatx4){0.f, 0.f, 0.f, 0.f};

  // wave w computes rows [32w, 32w+32) x all 128 cols; K=128 in 4 steps of 32
  #pragma unroll
  for (int kk = 0; kk < 4; ++kk) {
    int ko = kk * 32 + quad * 8;
    short8 a0 = *(const short8*)(xt + (wave * 32 +      l16) * LDSX + ko);
    short8 a1 = *(const short8*)(xt + (wave * 32 + 16 + l16) * LDSX + ko);
    #pragma unroll
    for (int ct = 0; ct < 8; ++ct) {
      short8 b = *(const short8*)(wt + (ct * 16 + l16) * LDSX + ko);
      acc[0][ct] = __builtin_amdgcn_mfma_f32_16x16x32_bf16(a0, b, acc[0][ct], 0, 0, 0);
      acc[1][ct] = __builtin_amdgcn_mfma_f32_16x16x32_bf16(a1, b, acc[1][ct], 0, 0, 0);
    }
  }

  __syncthreads();   // done reading xt/wt; reuse as g

  // epilogue: +b1, relu, write f32 to LDS.  C layout: col=lane&15, row=quad*4+reg
  #pragma unroll
  for (int ct = 0; ct < 8; ++ct) {
    float bias = b1[ct * 16 + l16];
    #pragma unroll
    for (int rt = 0; rt < 2; ++rt) {
      #pragma unroll
      for (int i = 0; i < 4; ++i) {
        float v = acc[rt][ct][i] + bias;
        v = fmaxf(v, 0.f);
        int row = wave * 32 + rt * 16 + quad * 4 + i;
        g[row * LDSG + ct * 16 + l16] = v;
      }
    }
  }
  __syncthreads();

  // s0 = last s with slices[s] <= r0  (uniform binary search)
  int l = 0, r = B + 1;
  while (l < r) { int m = (l + r) >> 1; if (slices[m] <= r0) l = m + 1; else r = m; }
  int s0 = l - 1;

  const int rEnd = min(r0 + TM, E);
  const int c2 = (tid & 63) * 2;      // column pair
  const int rg = tid >> 6;            // row group 0..3

  for (int s = s0; s < B && slices[s] < rEnd; ++s) {
    int lo = max(slices[s], r0) - r0;
    int hi = min(slices[s + 1], rEnd) - r0;
    if (hi <= lo) continue;           // empty run (uniform)
    float ax = 0.f, ay = 0.f;
    for (int rr = lo + rg; rr < hi; rr += 4) {
      float2 v = *(const float2*)(g + rr * LDSG + c2);
      ax += v.x; ay += v.y;
    }
    partial[rg * D + c2]     = ax;
    partial[rg * D + c2 + 1] = ay;
    __syncthreads();
    if (tid < D) {
      float t = partial[tid] + partial[D + tid] + partial[2 * D + tid] + partial[3 * D + tid];
      atomicAdd(&S[(size_t)s * D + tid], t);
    }
    __syncthreads();
  }
}

// ---------------- finish: out = (S/cnt)@W2+b2)@W3+b3 ; empty -> b3 ----------------
__global__ __launch_bounds__(128)
void finish_mlp(const float* __restrict__ S, const int* __restrict__ slices,
                const float* __restrict__ W2, const float* __restrict__ b2,
                const float* __restrict__ W3, const float* __restrict__ b3,
                float* __restrict__ out, int B)
{
  __shared__ float v0[D];
  __shared__ float v1[D];
  int s = blockIdx.x;
  int j = threadIdx.x;
  int c0 = slices[s], c1 = slices[s + 1];
  int cnt = c1 - c0;
  if (cnt <= 0) { out[s * D + j] = b3[j]; return; }   // uniform branch
  v0[j] = S[s * D + j] * (1.f / (float)cnt);
  __syncthreads();
  float a = b2[j];
  #pragma unroll 8
  for (int k = 0; k < D; ++k) a = fmaf(v0[k], W2[k * D + j], a);
  v1[j] = a;
  __syncthreads();
  float o = b3[j];
  #pragma unroll 8
  for (int k = 0; k < D; ++k) o = fmaf(v1[k], W3[k * D + j], o);
  out[s * D + j] = o;
}

extern "C" void kernel_launch(void* const* d_in, const int* in_sizes, int n_in,
                              void* d_out, int out_size, void* d_ws, size_t ws_size,
                              hipStream_t stream) {
  const float* x1     = (const float*)d_in[0];
  const int*   slices = (const int*)d_in[1];
  const float* W1     = (const float*)d_in[2];
  const float* b1     = (const float*)d_in[3];
  const float* W2     = (const float*)d_in[4];
  const float* b2     = (const float*)d_in[5];
  const float* W3     = (const float*)d_in[6];
  const float* b3     = (const float*)d_in[7];
  float* out = (float*)d_out;

  const int E = in_sizes[0] / D;
  const int B = in_sizes[1] - 1;

  float* S   = (float*)d_ws;                               // B*D f32
  u16*   W1T = (u16*)((char*)d_ws + (size_t)B * D * 4);    // D*D bf16

  int nS = B * D;
  prep_kernel<<<(nS + 255) / 256, 256, 0, stream>>>(W1, W1T, S, nS);

  int nblk = (E + TM - 1) / TM;
  fused_mlp_segsum<<<nblk, 256, 0, stream>>>(x1, slices, W1T, b1, S, E, B);

  finish_mlp<<<B, D, 0, stream>>>(S, slices, W2, b2, W3, b3, out, B);
}

// Round 2
// 675.158 us; speedup vs baseline: 1.1493x; 1.1493x over previous
//
#include <hip/hip_runtime.h>
#include <hip/hip_bf16.h>

typedef __attribute__((ext_vector_type(8))) short short8;
typedef __attribute__((ext_vector_type(4))) float floatx4;
typedef unsigned short u16;
typedef unsigned int u32;

#define D 128          // IN == OUT == 128
#define TM 64          // rows per tile
#define NT 4           // tiles per block chunk
#define CHUNK (TM*NT)  // 256 rows per block
#define LDSX 136       // padded row stride (u16 elements): stride 272B, even bank spread

static __device__ __forceinline__ u16 f2bf(float f) {
  union { float f; u32 u; } v; v.f = f;
  u32 r = v.u + 0x7fffu + ((v.u >> 16) & 1u);   // RNE round to bf16
  return (u16)(r >> 16);
}

// ---------------- prep: zero S, build W1^T in bf16 ----------------
__global__ void prep_kernel(const float* __restrict__ W1, u16* __restrict__ W1T,
                            float* __restrict__ S, int nS)
{
  int t = blockIdx.x * blockDim.x + threadIdx.x;
  if (t < D * D) {
    int k = t >> 7;          // W1 row (input dim)
    int n = t & (D - 1);     // W1 col (output dim)
    W1T[n * D + k] = f2bf(W1[t]);
  }
  if (t < nS) S[t] = 0.f;
}

// ---------------- main: g = relu(x@W1+b1), segment-sum into S ----------------
// Block: 256 threads (4 waves). Wave w owns output cols [32w, 32w+32) (ct=2w,2w+1).
// W1^T fragments live in VGPRs; LDS holds only a double-buffered 64x128 bf16 x-tile.
// Segment sums reduced in registers (MFMA C-layout) + shfl_xor + atomicAdd.
__global__ __launch_bounds__(256, 3)
void fused_mlp_segsum(const float* __restrict__ x1,
                      const int* __restrict__ slices,
                      const u16* __restrict__ W1T,
                      const float* __restrict__ b1,
                      float* __restrict__ S,
                      int E, int B)
{
  __shared__ __align__(16) u16 xt[2][TM * LDSX];   // 2*64*136*2 = 34816 B

  const int tid  = threadIdx.x;
  const int wv   = tid >> 6;
  const int lane = tid & 63;
  const int quad = lane >> 4;
  const int l16  = lane & 15;

  const int chunkStart = blockIdx.x * CHUNK;
  const int chunkEnd   = min(chunkStart + CHUNK, E);
  const int ntiles     = (chunkEnd - chunkStart + TM - 1) / TM;

  // --- B fragments (W1^T) into registers: ct = 2*wv + c ---
  // B-frag layout (verified r1): lane(quad,l16) holds W1T[ct*16+l16][kk*32+quad*8 .. +7]
  short8 bf[2][4];
  #pragma unroll
  for (int c = 0; c < 2; ++c)
    #pragma unroll
    for (int kk = 0; kk < 4; ++kk)
      bf[c][kk] = *(const short8*)(W1T + ((2 * wv + c) * 16 + l16) * D + kk * 32 + quad * 8);

  float bias[2] = { b1[wv * 32 + l16], b1[wv * 32 + 16 + l16] };

  // --- current segment: last s with slices[s] <= chunkStart ---
  int l = 0, r = B + 1;
  while (l < r) { int m = (l + r) >> 1; if (slices[m] <= chunkStart) l = m + 1; else r = m; }
  int cur = l - 1;
  float racc0 = 0.f, racc1 = 0.f;

  // --- stage tile 0 ---
  {
    #pragma unroll
    for (int i = 0; i < 8; ++i) {
      int f = tid + i * 256;
      int row = chunkStart + (f >> 5);
      int c = (f & 31) * 4;
      int rr = min(row, E - 1);
      float4 v = *(const float4*)(x1 + (size_t)rr * D + c);
      if (row >= E) { v.x = 0.f; v.y = 0.f; v.z = 0.f; v.w = 0.f; }
      uint2 pk;
      pk.x = (u32)f2bf(v.x) | ((u32)f2bf(v.y) << 16);
      pk.y = (u32)f2bf(v.z) | ((u32)f2bf(v.w) << 16);
      *(uint2*)(&xt[0][(f >> 5) * LDSX + c]) = pk;
    }
  }
  __syncthreads();

  for (int t = 0; t < ntiles; ++t) {
    const int base = chunkStart + t * TM;

    // ---- issue prefetch loads for tile t+1 (land during compute) ----
    float4 ld[8];
    const bool havePf = (t + 1 < ntiles);
    if (havePf) {
      int nb = base + TM;
      #pragma unroll
      for (int i = 0; i < 8; ++i) {
        int f = tid + i * 256;
        int row = nb + (f >> 5);
        int rr = min(row, E - 1);
        ld[i] = *(const float4*)(x1 + (size_t)rr * D + (f & 31) * 4);
        if (row >= E) { ld[i].x = 0.f; ld[i].y = 0.f; ld[i].z = 0.f; ld[i].w = 0.f; }
      }
    }

    // ---- MFMA on buffer t&1 ----
    const u16* xb = xt[t & 1];
    floatx4 acc[4][2];
    #pragma unroll
    for (int rt = 0; rt < 4; ++rt)
      #pragma unroll
      for (int c = 0; c < 2; ++c)
        acc[rt][c] = (floatx4){0.f, 0.f, 0.f, 0.f};

    #pragma unroll
    for (int kk = 0; kk < 4; ++kk) {
      #pragma unroll
      for (int rt = 0; rt < 4; ++rt) {
        short8 a = *(const short8*)(xb + (rt * 16 + l16) * LDSX + kk * 32 + quad * 8);
        acc[rt][0] = __builtin_amdgcn_mfma_f32_16x16x32_bf16(a, bf[0][kk], acc[rt][0], 0, 0, 0);
        acc[rt][1] = __builtin_amdgcn_mfma_f32_16x16x32_bf16(a, bf[1][kk], acc[rt][1], 0, 0, 0);
      }
    }

    // ---- bias + relu in place; C layout: row(in 16-tile) = quad*4+i, col = ct*16+l16 ----
    #pragma unroll
    for (int rt = 0; rt < 4; ++rt)
      #pragma unroll
      for (int c = 0; c < 2; ++c)
        #pragma unroll
        for (int i = 0; i < 4; ++i)
          acc[rt][c][i] = fmaxf(acc[rt][c][i] + bias[c], 0.f);

    // ---- segment reduction over this tile's rows ----
    const int tileHi = min(base + TM, chunkEnd);

    auto segAdd = [&](int loR, int hiR) {   // tile-relative row range [loR,hiR)
      #pragma unroll
      for (int rt = 0; rt < 4; ++rt)
        #pragma unroll
        for (int i = 0; i < 4; ++i) {
          int rowOff = rt * 16 + quad * 4 + i;
          bool in = (rowOff >= loR) && (rowOff < hiR);
          racc0 += in ? acc[rt][0][i] : 0.f;
          racc1 += in ? acc[rt][1][i] : 0.f;
        }
    };
    auto flushSeg = [&](int s) {
      float t0 = racc0, t1 = racc1;
      t0 += __shfl_xor(t0, 16); t0 += __shfl_xor(t0, 32);
      t1 += __shfl_xor(t1, 16); t1 += __shfl_xor(t1, 32);
      if (quad == 0) {
        atomicAdd(&S[s * D + wv * 32 + l16], t0);
        atomicAdd(&S[s * D + wv * 32 + 16 + l16], t1);
      }
    };

    // segments ending within this tile
    while (cur < B) {
      int segEnd = slices[cur + 1];
      if (segEnd > tileHi) break;
      int lo = max(slices[cur], base);
      if (segEnd > lo) segAdd(lo - base, segEnd - base);
      flushSeg(cur);
      racc0 = 0.f; racc1 = 0.f;
      ++cur;
    }
    // segment continuing past this tile
    if (cur < B) {
      int lo = max(slices[cur], base);
      if (lo < tileHi) {
        if (lo == base && tileHi == base + TM) {
          #pragma unroll
          for (int rt = 0; rt < 4; ++rt)
            #pragma unroll
            for (int i = 0; i < 4; ++i) { racc0 += acc[rt][0][i]; racc1 += acc[rt][1][i]; }
        } else {
          segAdd(lo - base, tileHi - base);
        }
      }
    }

    // ---- convert + write prefetched tile into other buffer ----
    if (havePf) {
      u16* dst = xt[(t + 1) & 1];
      #pragma unroll
      for (int i = 0; i < 8; ++i) {
        int f = tid + i * 256;
        uint2 pk;
        pk.x = (u32)f2bf(ld[i].x) | ((u32)f2bf(ld[i].y) << 16);
        pk.y = (u32)f2bf(ld[i].z) | ((u32)f2bf(ld[i].w) << 16);
        *(uint2*)(&dst[(f >> 5) * LDSX + (f & 31) * 4]) = pk;
      }
    }
    __syncthreads();
  }

  // final flush for the segment spilling past chunkEnd
  if (cur < B && slices[cur] < chunkEnd) {
    float t0 = racc0, t1 = racc1;
    t0 += __shfl_xor(t0, 16); t0 += __shfl_xor(t0, 32);
    t1 += __shfl_xor(t1, 16); t1 += __shfl_xor(t1, 32);
    if (quad == 0) {
      atomicAdd(&S[cur * D + wv * 32 + l16], t0);
      atomicAdd(&S[cur * D + wv * 32 + 16 + l16], t1);
    }
  }
}

// ---------------- finish: out = ((S/cnt)@W2+b2)@W3+b3 ; empty -> b3 ----------------
__global__ __launch_bounds__(128)
void finish_mlp(const float* __restrict__ S, const int* __restrict__ slices,
                const float* __restrict__ W2, const float* __restrict__ b2,
                const float* __restrict__ W3, const float* __restrict__ b3,
                float* __restrict__ out, int B)
{
  __shared__ float v0[D];
  __shared__ float v1[D];
  int s = blockIdx.x;
  int j = threadIdx.x;
  int c0 = slices[s], c1 = slices[s + 1];
  int cnt = c1 - c0;
  if (cnt <= 0) { out[s * D + j] = b3[j]; return; }   // uniform branch
  v0[j] = S[s * D + j] * (1.f / (float)cnt);
  __syncthreads();
  float a = b2[j];
  #pragma unroll 8
  for (int k = 0; k < D; ++k) a = fmaf(v0[k], W2[k * D + j], a);
  v1[j] = a;
  __syncthreads();
  float o = b3[j];
  #pragma unroll 8
  for (int k = 0; k < D; ++k) o = fmaf(v1[k], W3[k * D + j], o);
  out[s * D + j] = o;
}

extern "C" void kernel_launch(void* const* d_in, const int* in_sizes, int n_in,
                              void* d_out, int out_size, void* d_ws, size_t ws_size,
                              hipStream_t stream) {
  const float* x1     = (const float*)d_in[0];
  const int*   slices = (const int*)d_in[1];
  const float* W1     = (const float*)d_in[2];
  const float* b1     = (const float*)d_in[3];
  const float* W2     = (const float*)d_in[4];
  const float* b2     = (const float*)d_in[5];
  const float* W3     = (const float*)d_in[6];
  const float* b3     = (const float*)d_in[7];
  float* out = (float*)d_out;

  const int E = in_sizes[0] / D;
  const int B = in_sizes[1] - 1;

  float* S   = (float*)d_ws;                               // B*D f32
  u16*   W1T = (u16*)((char*)d_ws + (size_t)B * D * 4);    // D*D bf16

  int nS = B * D;
  prep_kernel<<<(nS + 255) / 256, 256, 0, stream>>>(W1, W1T, S, nS);

  int nblk = (E + CHUNK - 1) / CHUNK;
  fused_mlp_segsum<<<nblk, 256, 0, stream>>>(x1, slices, W1T, b1, S, E, B);

  finish_mlp<<<B, D, 0, stream>>>(S, slices, W2, b2, W3, b3, out, B);
}